// Round 2
// 1777.046 us; speedup vs baseline: 1.0605x; 1.0605x over previous
//
#include <hip/hip_runtime.h>
#include <hip/hip_bf16.h>

// Problem constants
#define Hdim 1024
#define Nb   2048
#define Lsteps 48

typedef unsigned short ushort_t;
typedef short bf16x8 __attribute__((ext_vector_type(8)));   // 8 bf16 (4 VGPRs)
typedef float f32x4 __attribute__((ext_vector_type(4)));    // 4 fp32 accum

typedef __attribute__((address_space(3))) unsigned int lds_u32;
typedef const __attribute__((address_space(1))) unsigned int glb_u32;

__device__ __forceinline__ void gll16(const void* g, void* l) {
    // async global->LDS DMA, 16 B/lane; LDS dest = wave-uniform base + lane*16
    __builtin_amdgcn_global_load_lds((glb_u32*)g, (lds_u32*)l, 16, 0, 0);
}

// RTN-even fp32 -> bf16 bits
__device__ __forceinline__ ushort_t f2bf(float x) {
    unsigned u = __builtin_bit_cast(unsigned, x);
    unsigned r = u + 0x7fffu + ((u >> 16) & 1u);
    return (ushort_t)(r >> 16);
}

// v_rcp_f32: ~1 ulp approx — plenty for the absmax budget; avoids the
// ~10-instr IEEE div_scale/div_fmas/div_fixup sequence (5 divs x 16 cells/thread)
__device__ __forceinline__ float frcp(float x) { return __builtin_amdgcn_rcpf(x); }

__device__ __forceinline__ float fsigmoid(float x) {
    return frcp(1.0f + __expf(-x));
}
__device__ __forceinline__ float ftanh(float x) {
    float xm = fminf(fmaxf(x, -15.0f), 15.0f);
    float e = __expf(2.0f * xm);
    return (e - 1.0f) * frcp(e + 1.0f);
}

__device__ __forceinline__ f32x4 mfma16(bf16x8 a, bf16x8 b, f32x4 c) {
    return __builtin_amdgcn_mfma_f32_16x16x32_bf16(a, b, c, 0, 0, 0);
}

// ---------------------------------------------------------------------------
// Prep kernels
// ---------------------------------------------------------------------------
__global__ __launch_bounds__(256) void prep_w(const float* __restrict__ W,
                                              ushort_t* __restrict__ Wb) {
    int i = blockIdx.x * 256 + threadIdx.x;   // 4M elements
    Wb[i] = f2bf(W[i]);
}

__global__ __launch_bounds__(256) void prep_h(const float* __restrict__ h_in,
                                              ushort_t* __restrict__ h0,
                                              const float* __restrict__ b_ih,
                                              const float* __restrict__ b_hh,
                                              float* __restrict__ bias) {
    int i = blockIdx.x * 256 + threadIdx.x;   // 2M elements
    h0[i] = f2bf(h_in[i]);
    if (i < 4 * Hdim) bias[i] = b_ih[i] + b_hh[i];
}

// ---------------------------------------------------------------------------
// Fused step: tile = 128 n-rows x 32 j-cols x 4 gates (GEMM 128x128), BK=64.
// 2-phase double-buffered pipeline (T3 minimum recipe):
//   STAGE(buf0,0); sync;
//   loop: STAGE(next tile into other buf); COMPUTE(current buf); sync;
// One barrier per K-tile; the compiler's vmcnt(0) drain before s_barrier now
// happens AFTER the 32-MFMA compute phase, so global->LDS latency is hidden.
//
// Race audit: STAGE(b) only writes buf b after the barrier that retired all
// ds_reads of buf b (lgkmcnt(0) precedes s_barrier); COMPUTE(b) only runs
// after the barrier whose vmcnt(0) drained STAGE(b)'s global_load_lds.
//
// XCD-aware block remap: xcd = blockIdx % 8, each XCD gets a 4 MB
// (2 MB h-slice + 2 MB W-slice) working set resident in its private L2.
// ---------------------------------------------------------------------------
__global__ __launch_bounds__(256) void lstm_step(
    const ushort_t* __restrict__ hsrc,   // [Nb][Hdim] bf16 bits
    ushort_t* __restrict__ hdst,         // [Nb][Hdim] bf16 bits
    const ushort_t* __restrict__ Wb,     // [4*Hdim][Hdim] bf16 bits
    const float* __restrict__ bias,      // [4*Hdim]
    float* __restrict__ cst,             // [Nb][Hdim] fp32 cell state
    float* __restrict__ tmp)             // [Nb][Hdim] fp32 h output slot
{
    // Double-buffered: 2 x (128 rows x 64 elems = 16 KB) per operand = 64 KB.
    // 2 blocks/CU -> 128 KB of 160 KB LDS.
    __shared__ __align__(16) ushort_t As[2][128 * 64];
    __shared__ __align__(16) ushort_t Bs[2][128 * 64];

    const int tid  = threadIdx.x;
    const int lane = tid & 63;
    const int wid  = tid >> 6;
    const int wr   = wid >> 1;            // n half (0..1)
    const int wc   = wid & 1;             // j half (0..1)

    // XCD-aware remap: p%8 = XCD (HW round-robin), 64 slots per XCD.
    const int p    = blockIdx.x;
    const int xcd  = p & 7;
    const int slot = p >> 3;              // 0..63
    const int jb   = (xcd >> 1) * 8 + (slot & 7);   // 0..31
    const int nb   = (xcd & 1) * 8 + (slot >> 3);   // 0..15
    const int n0   = nb * 128;
    const int j0   = jb * 32;

    f32x4 acc[4][4];
#pragma unroll
    for (int g = 0; g < 4; ++g)
#pragma unroll
        for (int ri = 0; ri < 4; ++ri)
            acc[g][ri] = (f32x4){0.f, 0.f, 0.f, 0.f};

    // staging geometry: per gll instr, 8 rows x 128 B; lane -> (row, chunk)
    const int srow8  = lane >> 3;                      // row within group of 8
    const int schunk = (lane & 7) ^ srow8;             // swizzled 16B chunk
    const int choff  = schunk * 8;                     // elem offset in row

    // per-lane global row base pointers (row stride Hdim elems)
    const ushort_t* aGlob = hsrc + (size_t)(n0 + wid * 32 + srow8) * Hdim + choff;
    const ushort_t* bGlob = Wb + (size_t)(wid * Hdim + j0 + srow8) * Hdim + choff;

    // ds_read swizzle: row&7 == lr&7 for both A and B fragment rows
    const int lr   = lane & 15;
    const int rsw  = lr & 7;
    const int cq   = lane >> 4;                        // base chunk 0..3

    auto STAGE = [&](int buf, int it) {
        const int k0 = it * 64;
#pragma unroll
        for (int ii = 0; ii < 4; ++ii)
            gll16(aGlob + (size_t)ii * 8 * Hdim + k0, &As[buf][(wid * 32 + ii * 8) * 64]);
#pragma unroll
        for (int ii = 0; ii < 4; ++ii)
            gll16(bGlob + (size_t)ii * 8 * Hdim + k0, &Bs[buf][(wid * 32 + ii * 8) * 64]);
    };

    auto COMPUTE = [&](int buf) {
#pragma unroll
        for (int kh = 0; kh < 2; ++kh) {
            const int ch = ((cq + kh * 4) ^ rsw) * 8;  // swizzled elem offset
            bf16x8 af[4], bfr[4];
#pragma unroll
            for (int ri = 0; ri < 4; ++ri) {
                int row = wr * 64 + ri * 16 + lr;
                af[ri] = *(const bf16x8*)&As[buf][row * 64 + ch];
            }
#pragma unroll
            for (int g = 0; g < 4; ++g) {
                int u = g * 32 + wc * 16 + lr;
                bfr[g] = *(const bf16x8*)&Bs[buf][u * 64 + ch];
            }
#pragma unroll
            for (int g = 0; g < 4; ++g)
#pragma unroll
                for (int ri = 0; ri < 4; ++ri)
                    acc[g][ri] = mfma16(af[ri], bfr[g], acc[g][ri]);
        }
    };

    // ---- 2-phase pipeline over 16 K-tiles (K=1024, BK=64) ----
    STAGE(0, 0);
    __syncthreads();                      // vmcnt(0) drain + barrier: buf0 ready
#pragma unroll 1
    for (int it = 0; it < 14; it += 2) {
        STAGE(1, it + 1);                 // prefetch flies under compute
        COMPUTE(0);
        __syncthreads();                  // drains prefetch, buf1 ready; buf0 free
        STAGE(0, it + 2);
        COMPUTE(1);
        __syncthreads();
    }
    STAGE(1, 15);
    COMPUTE(0);
    __syncthreads();
    COMPUTE(1);                           // last tile: no prefetch, no barrier

    // Epilogue: C/D layout col=lane&15, row=(lane>>4)*4+reg  [m89-verified]
    const int q4 = (lane >> 4) * 4;
    const int j  = j0 + wc * 16 + lr;
    const float bi = bias[j];
    const float bf = bias[Hdim + j];
    const float bg = bias[2 * Hdim + j];
    const float bo = bias[3 * Hdim + j];
#pragma unroll
    for (int ri = 0; ri < 4; ++ri)
#pragma unroll
        for (int q = 0; q < 4; ++q) {
            int n = n0 + wr * 64 + ri * 16 + q4 + q;
            float gi = fsigmoid(acc[0][ri][q] + bi);
            float gf = fsigmoid(acc[1][ri][q] + bf);
            float gg = ftanh(acc[2][ri][q] + bg);
            float go = fsigmoid(acc[3][ri][q] + bo);
            size_t idx = (size_t)n * Hdim + j;
            float cn = gf * cst[idx] + gi * gg;
            cst[idx] = cn;
            float hv = go * ftanh(cn);
            hdst[idx] = f2bf(hv);
            tmp[idx] = hv;
        }
}

// ---------------------------------------------------------------------------
// Flush: tmp[16][Nb][Hdim] -> out[n][j][t0 : t0+16]  (full 64B lines)
// ---------------------------------------------------------------------------
__global__ __launch_bounds__(256) void flush16(const float* __restrict__ tmp,
                                               float* __restrict__ out, int t0) {
    int idx = blockIdx.x * 256 + threadIdx.x;   // 0 .. Nb*Hdim-1
    float v[16];
#pragma unroll
    for (int s = 0; s < 16; ++s)
        v[s] = tmp[(size_t)s * (Nb * Hdim) + idx];
    float4* dst = (float4*)(out + (size_t)idx * Lsteps + t0);
#pragma unroll
    for (int s = 0; s < 4; ++s)
        dst[s] = make_float4(v[4 * s], v[4 * s + 1], v[4 * s + 2], v[4 * s + 3]);
}

// ---------------------------------------------------------------------------
extern "C" void kernel_launch(void* const* d_in, const int* in_sizes, int n_in,
                              void* d_out, int out_size, void* d_ws, size_t ws_size,
                              hipStream_t stream) {
    const float* h_in = (const float*)d_in[0];
    const float* W    = (const float*)d_in[1];
    const float* b_ih = (const float*)d_in[2];
    const float* b_hh = (const float*)d_in[3];
    float* out = (float*)d_out;

    // Workspace layout (bytes):
    //   Wb     @ 0          : 4096*1024*2 = 8388608
    //   h0     @ 8388608    : 2048*1024*2 = 4194304
    //   h1     @ 12582912   : 2048*1024*2 = 4194304
    //   c      @ 16777216   : 2048*1024*4 = 8388608
    //   bias   @ 25165824   : 4096*4      = 16384
    //   tmp16  @ 25182208   : 16*2048*1024*4 = 134217728
    char* ws = (char*)d_ws;
    ushort_t* Wb   = (ushort_t*)(ws);
    ushort_t* h0   = (ushort_t*)(ws + 8388608);
    ushort_t* h1   = (ushort_t*)(ws + 12582912);
    float*    cst  = (float*)(ws + 16777216);
    float*    bias = (float*)(ws + 25165824);
    float*    tmp16= (float*)(ws + 25182208);

    hipMemsetAsync(cst, 0, (size_t)Nb * Hdim * sizeof(float), stream);

    prep_w<<<(4 * Hdim * Hdim) / 256, 256, 0, stream>>>(W, Wb);
    prep_h<<<(Nb * Hdim) / 256, 256, 0, stream>>>(h_in, h0, b_ih, b_hh, bias);

    for (int t = 0; t < Lsteps; ++t) {
        const ushort_t* hs = (t & 1) ? h1 : h0;
        ushort_t*       hd = (t & 1) ? h0 : h1;
        float* tslot = tmp16 + (size_t)(t & 15) * (Nb * Hdim);
        lstm_step<<<512, 256, 0, stream>>>(hs, hd, Wb, bias, cst, tslot);
        if ((t & 15) == 15) {
            flush16<<<(Nb * Hdim) / 256, 256, 0, stream>>>(tmp16, out, t - 15);
        }
    }
}

// Round 3
// 1724.436 us; speedup vs baseline: 1.0929x; 1.0305x over previous
//
#include <hip/hip_runtime.h>
#include <hip/hip_bf16.h>

// Problem constants
#define Hdim 1024
#define Nb   2048
#define Lsteps 48

typedef unsigned short ushort_t;
typedef short bf16x8 __attribute__((ext_vector_type(8)));   // 8 bf16 (4 VGPRs)
typedef float f32x4 __attribute__((ext_vector_type(4)));    // 4 fp32 accum

typedef __attribute__((address_space(3))) unsigned int lds_u32;
typedef const __attribute__((address_space(1))) unsigned int glb_u32;

__device__ __forceinline__ void gll16(const void* g, void* l) {
    // async global->LDS DMA, 16 B/lane; LDS dest = wave-uniform base + lane*16
    __builtin_amdgcn_global_load_lds((glb_u32*)g, (lds_u32*)l, 16, 0, 0);
}

// RTN-even fp32 -> bf16 bits
__device__ __forceinline__ ushort_t f2bf(float x) {
    unsigned u = __builtin_bit_cast(unsigned, x);
    unsigned r = u + 0x7fffu + ((u >> 16) & 1u);
    return (ushort_t)(r >> 16);
}

// v_rcp_f32: ~1 ulp approx — plenty for the absmax budget; avoids the
// ~10-instr IEEE div sequence (5 divs x 16 cells/thread)
__device__ __forceinline__ float frcp(float x) { return __builtin_amdgcn_rcpf(x); }

__device__ __forceinline__ float fsigmoid(float x) {
    return frcp(1.0f + __expf(-x));
}
__device__ __forceinline__ float ftanh(float x) {
    float xm = fminf(fmaxf(x, -15.0f), 15.0f);
    float e = __expf(2.0f * xm);
    return (e - 1.0f) * frcp(e + 1.0f);
}

__device__ __forceinline__ f32x4 mfma16(bf16x8 a, bf16x8 b, f32x4 c) {
    return __builtin_amdgcn_mfma_f32_16x16x32_bf16(a, b, c, 0, 0, 0);
}

// Counted waitcnt + raw barrier (T4): loads stay in flight ACROSS barriers.
#define VMCNT8   asm volatile("s_waitcnt vmcnt(8)" ::: "memory")
#define VMCNT0   asm volatile("s_waitcnt vmcnt(0)" ::: "memory")
#define LGKMCNT0 asm volatile("s_waitcnt lgkmcnt(0)" ::: "memory")

// ---------------------------------------------------------------------------
// Prep kernels
// ---------------------------------------------------------------------------
__global__ __launch_bounds__(256) void prep_w(const float* __restrict__ W,
                                              ushort_t* __restrict__ Wb) {
    int i = blockIdx.x * 256 + threadIdx.x;   // 4M elements
    Wb[i] = f2bf(W[i]);
}

__global__ __launch_bounds__(256) void prep_h(const float* __restrict__ h_in,
                                              ushort_t* __restrict__ h0,
                                              const float* __restrict__ b_ih,
                                              const float* __restrict__ b_hh,
                                              float* __restrict__ bias) {
    int i = blockIdx.x * 256 + threadIdx.x;   // 2M elements
    h0[i] = f2bf(h_in[i]);
    if (i < 4 * Hdim) bias[i] = b_ih[i] + b_hh[i];
}

// ---------------------------------------------------------------------------
// Fused step: tile = 128 n-rows x 32 j-cols x 4 gates (GEMM 128x128), BK=64.
//
// Depth-2 counted-vmcnt pipeline (T3 minimum + T4):
//   STAGE(0,0); STAGE(1,1);                     // 16 loads in flight/wave
//   for t: { vmcnt(8); barrier;                 // tile t landed; t+1 stays in flight
//            setprio(1); COMPUTE(t&1); setprio(0);
//            lgkmcnt(0); barrier;               // all reads of buf done -> safe to overwrite
//            STAGE(t&1, t+2); }                 // issued here, consumed 2 barriers later
// vmcnt never drains to 0 in the main loop (m218: T3's gain IS T4).
// Each wave issues its own 8 gll16 per tile; vmcnt is per-wave, barrier joins.
// Hoisted loop-invariant loads (bias) only extend the OLDEST side of the
// vmcnt queue -> correctness unaffected, tile t still guaranteed landed.
//
// XCD-aware block remap: xcd = blockIdx % 8, each XCD gets a 4 MB
// (2 MB h-slice + 2 MB W-slice) working set resident in its private L2.
// ---------------------------------------------------------------------------
__global__ __launch_bounds__(256) void lstm_step(
    const ushort_t* __restrict__ hsrc,   // [Nb][Hdim] bf16 bits
    ushort_t* __restrict__ hdst,         // [Nb][Hdim] bf16 bits
    const ushort_t* __restrict__ Wb,     // [4*Hdim][Hdim] bf16 bits
    const float* __restrict__ bias,      // [4*Hdim]
    float* __restrict__ cst,             // [Nb][Hdim] fp32 cell state
    float* __restrict__ tmp)             // [Nb][Hdim] fp32 h output slot
{
    // Double-buffered: 2 x (128 rows x 64 elems = 16 KB) per operand = 64 KB.
    // 2 blocks/CU -> 128 KB of 160 KB LDS.
    __shared__ __align__(16) ushort_t As[2][128 * 64];
    __shared__ __align__(16) ushort_t Bs[2][128 * 64];

    const int tid  = threadIdx.x;
    const int lane = tid & 63;
    const int wid  = tid >> 6;
    const int wr   = wid >> 1;            // n half (0..1)
    const int wc   = wid & 1;             // j half (0..1)

    // XCD-aware remap: p%8 = XCD (HW round-robin), 64 slots per XCD.
    const int p    = blockIdx.x;
    const int xcd  = p & 7;
    const int slot = p >> 3;              // 0..63
    const int jb   = (xcd >> 1) * 8 + (slot & 7);   // 0..31
    const int nb   = (xcd & 1) * 8 + (slot >> 3);   // 0..15
    const int n0   = nb * 128;
    const int j0   = jb * 32;

    f32x4 acc[4][4];
#pragma unroll
    for (int g = 0; g < 4; ++g)
#pragma unroll
        for (int ri = 0; ri < 4; ++ri)
            acc[g][ri] = (f32x4){0.f, 0.f, 0.f, 0.f};

    // staging geometry: per gll instr, 8 rows x 128 B; lane -> (row, chunk)
    const int srow8  = lane >> 3;                      // row within group of 8
    const int schunk = (lane & 7) ^ srow8;             // swizzled 16B chunk
    const int choff  = schunk * 8;                     // elem offset in row

    // per-lane global row base pointers (row stride Hdim elems)
    const ushort_t* aGlob = hsrc + (size_t)(n0 + wid * 32 + srow8) * Hdim + choff;
    const ushort_t* bGlob = Wb + (size_t)(wid * Hdim + j0 + srow8) * Hdim + choff;

    // ds_read swizzle: row&7 == lr&7 for both A and B fragment rows
    const int lr   = lane & 15;
    const int rsw  = lr & 7;
    const int cq   = lane >> 4;                        // base chunk 0..3

    auto STAGE = [&](int buf, int it) {
        const int k0 = it * 64;
#pragma unroll
        for (int ii = 0; ii < 4; ++ii)
            gll16(aGlob + (size_t)ii * 8 * Hdim + k0, &As[buf][(wid * 32 + ii * 8) * 64]);
#pragma unroll
        for (int ii = 0; ii < 4; ++ii)
            gll16(bGlob + (size_t)ii * 8 * Hdim + k0, &Bs[buf][(wid * 32 + ii * 8) * 64]);
    };

    auto COMPUTE = [&](int buf) {
#pragma unroll
        for (int kh = 0; kh < 2; ++kh) {
            const int ch = ((cq + kh * 4) ^ rsw) * 8;  // swizzled elem offset
            bf16x8 af[4], bfr[4];
#pragma unroll
            for (int ri = 0; ri < 4; ++ri) {
                int row = wr * 64 + ri * 16 + lr;
                af[ri] = *(const bf16x8*)&As[buf][row * 64 + ch];
            }
#pragma unroll
            for (int g = 0; g < 4; ++g) {
                int u = g * 32 + wc * 16 + lr;
                bfr[g] = *(const bf16x8*)&Bs[buf][u * 64 + ch];
            }
#pragma unroll
            for (int g = 0; g < 4; ++g)
#pragma unroll
                for (int ri = 0; ri < 4; ++ri)
                    acc[g][ri] = mfma16(af[ri], bfr[g], acc[g][ri]);
        }
    };

    // ---- depth-2 counted-vmcnt pipeline over 16 K-tiles (K=1024, BK=64) ----
    STAGE(0, 0);                            // vm in flight: 8
    STAGE(1, 1);                            // vm in flight: 16
#pragma unroll 1
    for (int t = 0; t < 16; ++t) {
        const int cur = t & 1;
        if (t < 15) { VMCNT8; } else { VMCNT0; }   // tile t landed; t+1 in flight
        __builtin_amdgcn_s_barrier();
        __builtin_amdgcn_s_setprio(1);
        COMPUTE(cur);
        __builtin_amdgcn_s_setprio(0);
        if (t < 15) {
            LGKMCNT0;                       // in-flight ds_reads of buf[cur] done
            __builtin_amdgcn_s_barrier();   // -> safe for everyone to overwrite
            if (t < 14) STAGE(cur, t + 2);  // stays in flight across 2 barriers
        }
    }

    // Epilogue: C/D layout col=lane&15, row=(lane>>4)*4+reg  [m89-verified]
    const int q4 = (lane >> 4) * 4;
    const int j  = j0 + wc * 16 + lr;
    const float bi = bias[j];
    const float bf = bias[Hdim + j];
    const float bg = bias[2 * Hdim + j];
    const float bo = bias[3 * Hdim + j];
#pragma unroll
    for (int ri = 0; ri < 4; ++ri)
#pragma unroll
        for (int q = 0; q < 4; ++q) {
            int n = n0 + wr * 64 + ri * 16 + q4 + q;
            float gi = fsigmoid(acc[0][ri][q] + bi);
            float gf = fsigmoid(acc[1][ri][q] + bf);
            float gg = ftanh(acc[2][ri][q] + bg);
            float go = fsigmoid(acc[3][ri][q] + bo);
            size_t idx = (size_t)n * Hdim + j;
            float cn = gf * cst[idx] + gi * gg;
            cst[idx] = cn;
            float hv = go * ftanh(cn);
            hdst[idx] = f2bf(hv);
            tmp[idx] = hv;
        }
}

// ---------------------------------------------------------------------------
// Flush: tmp[16][Nb][Hdim] -> out[n][j][t0 : t0+16]  (full 64B lines)
// ---------------------------------------------------------------------------
__global__ __launch_bounds__(256) void flush16(const float* __restrict__ tmp,
                                               float* __restrict__ out, int t0) {
    int idx = blockIdx.x * 256 + threadIdx.x;   // 0 .. Nb*Hdim-1
    float v[16];
#pragma unroll
    for (int s = 0; s < 16; ++s)
        v[s] = tmp[(size_t)s * (Nb * Hdim) + idx];
    float4* dst = (float4*)(out + (size_t)idx * Lsteps + t0);
#pragma unroll
    for (int s = 0; s < 4; ++s)
        dst[s] = make_float4(v[4 * s], v[4 * s + 1], v[4 * s + 2], v[4 * s + 3]);
}

// ---------------------------------------------------------------------------
extern "C" void kernel_launch(void* const* d_in, const int* in_sizes, int n_in,
                              void* d_out, int out_size, void* d_ws, size_t ws_size,
                              hipStream_t stream) {
    const float* h_in = (const float*)d_in[0];
    const float* W    = (const float*)d_in[1];
    const float* b_ih = (const float*)d_in[2];
    const float* b_hh = (const float*)d_in[3];
    float* out = (float*)d_out;

    // Workspace layout (bytes):
    //   Wb     @ 0          : 4096*1024*2 = 8388608
    //   h0     @ 8388608    : 2048*1024*2 = 4194304
    //   h1     @ 12582912   : 2048*1024*2 = 4194304
    //   c      @ 16777216   : 2048*1024*4 = 8388608
    //   bias   @ 25165824   : 4096*4      = 16384
    //   tmp16  @ 25182208   : 16*2048*1024*4 = 134217728
    char* ws = (char*)d_ws;
    ushort_t* Wb   = (ushort_t*)(ws);
    ushort_t* h0   = (ushort_t*)(ws + 8388608);
    ushort_t* h1   = (ushort_t*)(ws + 12582912);
    float*    cst  = (float*)(ws + 16777216);
    float*    bias = (float*)(ws + 25165824);
    float*    tmp16= (float*)(ws + 25182208);

    hipMemsetAsync(cst, 0, (size_t)Nb * Hdim * sizeof(float), stream);

    prep_w<<<(4 * Hdim * Hdim) / 256, 256, 0, stream>>>(W, Wb);
    prep_h<<<(Nb * Hdim) / 256, 256, 0, stream>>>(h_in, h0, b_ih, b_hh, bias);

    for (int t = 0; t < Lsteps; ++t) {
        const ushort_t* hs = (t & 1) ? h1 : h0;
        ushort_t*       hd = (t & 1) ? h0 : h1;
        float* tslot = tmp16 + (size_t)(t & 15) * (Nb * Hdim);
        lstm_step<<<512, 256, 0, stream>>>(hs, hd, Wb, bias, cst, tslot);
        if ((t & 15) == 15) {
            flush16<<<(Nb * Hdim) / 256, 256, 0, stream>>>(tmp16, out, t - 15);
        }
    }
}